// Round 1
// baseline (457.554 us; speedup 1.0000x reference)
//
#include <hip/hip_runtime.h>
#include <math.h>

#define DIM 10

// ---------------------------------------------------------------------------
// Kernel 1: single-thread setup. Computes, in fp64:
//   Wsym = W + W^T, V = inv(Wsym - I)
//   M = V Wsym V^T, N = V - I, c = -0.5 b
//   A = M - N N^T           (10x10, symmetric)
//   p = 2 M c + V b - 2 N (V^T c)
//   q = c M c^T + c.(Vb) - |cV|^2
// writes ws[0..99]=A, ws[100..109]=p, ws[110]=q
// ---------------------------------------------------------------------------
__global__ void harmon_setup(const float* __restrict__ W,
                             const float* __restrict__ b,
                             float* __restrict__ ws) {
    if (threadIdx.x != 0 || blockIdx.x != 0) return;

    double Ws[DIM][DIM], Aug[DIM][2 * DIM], Vv[DIM][DIM];
    for (int i = 0; i < DIM; i++)
        for (int j = 0; j < DIM; j++)
            Ws[i][j] = (double)W[i * DIM + j] + (double)W[j * DIM + i];

    // Augmented [Wsym - I | I]
    for (int i = 0; i < DIM; i++) {
        for (int j = 0; j < DIM; j++) {
            Aug[i][j] = Ws[i][j] - (i == j ? 1.0 : 0.0);
            Aug[i][DIM + j] = (i == j) ? 1.0 : 0.0;
        }
    }
    // Gauss-Jordan with partial pivoting
    for (int col = 0; col < DIM; col++) {
        int piv = col;
        double best = fabs(Aug[col][col]);
        for (int r2 = col + 1; r2 < DIM; r2++) {
            double v = fabs(Aug[r2][col]);
            if (v > best) { best = v; piv = r2; }
        }
        if (piv != col) {
            for (int j = 0; j < 2 * DIM; j++) {
                double t = Aug[col][j]; Aug[col][j] = Aug[piv][j]; Aug[piv][j] = t;
            }
        }
        double inv = 1.0 / Aug[col][col];
        for (int j = 0; j < 2 * DIM; j++) Aug[col][j] *= inv;
        for (int r2 = 0; r2 < DIM; r2++) {
            if (r2 == col) continue;
            double f = Aug[r2][col];
            if (f != 0.0)
                for (int j = 0; j < 2 * DIM; j++) Aug[r2][j] -= f * Aug[col][j];
        }
    }
    for (int i = 0; i < DIM; i++)
        for (int j = 0; j < DIM; j++) Vv[i][j] = Aug[i][DIM + j];

    double c[DIM], Vb[DIM], VW[DIM][DIM], M[DIM][DIM], Nm[DIM][DIM];
    for (int i = 0; i < DIM; i++) c[i] = -0.5 * (double)b[i];
    for (int i = 0; i < DIM; i++) {
        double s = 0;
        for (int j = 0; j < DIM; j++) s += Vv[i][j] * (double)b[j];
        Vb[i] = s;
    }
    for (int i = 0; i < DIM; i++)
        for (int k = 0; k < DIM; k++) {
            double s = 0;
            for (int j = 0; j < DIM; j++) s += Vv[i][j] * Ws[j][k];
            VW[i][k] = s;
        }
    for (int i = 0; i < DIM; i++)
        for (int k = 0; k < DIM; k++) {
            double s = 0;
            for (int j = 0; j < DIM; j++) s += VW[i][j] * Vv[k][j];
            M[i][k] = s;
        }
    for (int i = 0; i < DIM; i++)
        for (int j = 0; j < DIM; j++) Nm[i][j] = Vv[i][j] - (i == j ? 1.0 : 0.0);

    double A[DIM][DIM];
    for (int i = 0; i < DIM; i++)
        for (int k = 0; k < DIM; k++) {
            double s = 0;
            for (int j = 0; j < DIM; j++) s += Nm[i][j] * Nm[k][j];
            A[i][k] = M[i][k] - s;
        }

    double VTc[DIM]; // (cV)_t = sum_j c_j V[j][t]
    for (int t = 0; t < DIM; t++) {
        double s = 0;
        for (int j = 0; j < DIM; j++) s += Vv[j][t] * c[j];
        VTc[t] = s;
    }
    double p[DIM];
    for (int k = 0; k < DIM; k++) {
        double s = 0;
        for (int t = 0; t < DIM; t++) s += 2.0 * M[k][t] * c[t] - 2.0 * Nm[k][t] * VTc[t];
        p[k] = s + Vb[k];
    }
    double cMc = 0, cVb = 0, n0 = 0;
    for (int i = 0; i < DIM; i++) {
        for (int j = 0; j < DIM; j++) cMc += c[i] * M[i][j] * c[j];
        cVb += c[i] * Vb[i];
        n0 += VTc[i] * VTc[i];
    }
    double q = cMc + cVb - n0;

    for (int i = 0; i < DIM; i++)
        for (int j = 0; j < DIM; j++) ws[i * DIM + j] = (float)A[i][j];
    for (int i = 0; i < DIM; i++) ws[100 + i] = (float)p[i];
    ws[110] = (float)q;
}

// ---------------------------------------------------------------------------
// Kernel 2: one thread per (b,s) sample.
//   gather e1,e2 rows (5x float2 each), rel row; cc[k]=sum_j e1[j]*e2[(j+k)%10]
//   x = r * cc ; out = q + p.x + x A x
// ---------------------------------------------------------------------------
__global__ __launch_bounds__(256) void harmon_main(
    const int* __restrict__ samples, const float* __restrict__ ent,
    const float* __restrict__ rel, const float* __restrict__ ws,
    float* __restrict__ out, int n) {
    int tid = blockIdx.x * 256 + threadIdx.x;
    if (tid >= n) return;

    int i1 = samples[3 * tid + 0];
    int ir = samples[3 * tid + 1];
    int i2 = samples[3 * tid + 2];

    const float2* p1 = (const float2*)(ent + (size_t)i1 * DIM);
    const float2* p2 = (const float2*)(ent + (size_t)i2 * DIM);
    const float2* pr = (const float2*)(rel + (size_t)ir * DIM);

    float a[DIM], e[DIM], r[DIM];
#pragma unroll
    for (int i = 0; i < 5; i++) {
        float2 v1 = p1[i]; a[2 * i] = v1.x; a[2 * i + 1] = v1.y;
        float2 v2 = p2[i]; e[2 * i] = v2.x; e[2 * i + 1] = v2.y;
        float2 vr = pr[i]; r[2 * i] = vr.x; r[2 * i + 1] = vr.y;
    }

    float x[DIM];
#pragma unroll
    for (int k = 0; k < DIM; k++) {
        float s = 0.0f;
#pragma unroll
        for (int j = 0; j < DIM; j++) s = fmaf(a[j], e[(j + k) % DIM], s);
        x[k] = r[k] * s;
    }

    float acc = ws[110];
#pragma unroll
    for (int k = 0; k < DIM; k++) {
        float s = ws[100 + k];
#pragma unroll
        for (int t = 0; t < DIM; t++) s = fmaf(ws[k * DIM + t], x[t], s);
        acc = fmaf(x[k], s, acc);
    }
    out[tid] = acc;
}

extern "C" void kernel_launch(void* const* d_in, const int* in_sizes, int n_in,
                              void* d_out, int out_size, void* d_ws, size_t ws_size,
                              hipStream_t stream) {
    const int* samples = (const int*)d_in[0];
    const float* ent = (const float*)d_in[1];
    const float* rel = (const float*)d_in[2];
    const float* W = (const float*)d_in[3];
    const float* b = (const float*)d_in[4];
    float* out = (float*)d_out;
    float* ws = (float*)d_ws;

    int n = in_sizes[0] / 3; // B*S samples

    harmon_setup<<<1, 64, 0, stream>>>(W, b, ws);
    int blocks = (n + 255) / 256;
    harmon_main<<<blocks, 256, 0, stream>>>(samples, ent, rel, ws, out, n);
}

// Round 2
// 101.098 us; speedup vs baseline: 4.5258x; 4.5258x over previous
//
#include <hip/hip_runtime.h>
#include <math.h>

#define DIM 10

// ---------------------------------------------------------------------------
// Kernel 1: one-block parallel setup (fp64 in LDS). Computes:
//   Wsym = W + W^T, V = inv(Wsym - I)
//   M = V Wsym V^T, N = V - I, c = -0.5 b
//   A = M - N N^T
//   p = 2 M c + V b - 2 N (V^T c)
//   q = c M c + c.(Vb) - |V^T c|^2
// writes ws[0..99]=A, ws[100..109]=p, ws[110]=q
// ---------------------------------------------------------------------------
__global__ __launch_bounds__(128) void harmon_setup(const float* __restrict__ W,
                                                    const float* __restrict__ b,
                                                    float* __restrict__ ws) {
    __shared__ double Ws[DIM][DIM];
    __shared__ double Aug[DIM][2 * DIM];
    __shared__ double Vv[DIM][DIM];
    __shared__ double VW[DIM][DIM];
    __shared__ double M[DIM][DIM];
    __shared__ double colv[DIM];
    __shared__ double cvec[DIM], Vb[DIM], VTc[DIM];
    __shared__ int piv_s;

    const int t = threadIdx.x;

    // Ws and augmented [Wsym - I | I]
    for (int idx = t; idx < DIM * DIM; idx += 128) {
        int i = idx / DIM, j = idx % DIM;
        double w = (double)W[i * DIM + j] + (double)W[j * DIM + i];
        Ws[i][j] = w;
        Aug[i][j] = w - (i == j ? 1.0 : 0.0);
        Aug[i][DIM + j] = (i == j) ? 1.0 : 0.0;
    }
    if (t < DIM) cvec[t] = -0.5 * (double)b[t];
    __syncthreads();

    // Gauss-Jordan with partial pivoting, row-ops parallel over 200 elements
    for (int col = 0; col < DIM; col++) {
        if (t == 0) {
            int piv = col;
            double best = fabs(Aug[col][col]);
            for (int r = col + 1; r < DIM; r++) {
                double v = fabs(Aug[r][col]);
                if (v > best) { best = v; piv = r; }
            }
            piv_s = piv;
        }
        __syncthreads();
        int piv = piv_s;
        if (piv != col && t < 2 * DIM) {
            double tmp = Aug[col][t]; Aug[col][t] = Aug[piv][t]; Aug[piv][t] = tmp;
        }
        __syncthreads();
        if (t < DIM) colv[t] = Aug[t][col];
        __syncthreads();
        if (t < 2 * DIM) Aug[col][t] /= colv[col];
        __syncthreads();
        for (int idx = t; idx < DIM * 2 * DIM; idx += 128) {
            int r = idx / (2 * DIM), j = idx % (2 * DIM);
            if (r != col) Aug[r][j] -= colv[r] * Aug[col][j];
        }
        __syncthreads();
    }

    for (int idx = t; idx < DIM * DIM; idx += 128) {
        int i = idx / DIM, j = idx % DIM;
        Vv[i][j] = Aug[i][DIM + j];
    }
    __syncthreads();

    // VW = V * Wsym
    for (int idx = t; idx < DIM * DIM; idx += 128) {
        int i = idx / DIM, k = idx % DIM;
        double s = 0;
        for (int j = 0; j < DIM; j++) s += Vv[i][j] * Ws[j][k];
        VW[i][k] = s;
    }
    __syncthreads();

    // M = VW * V^T
    for (int idx = t; idx < DIM * DIM; idx += 128) {
        int i = idx / DIM, k = idx % DIM;
        double s = 0;
        for (int j = 0; j < DIM; j++) s += VW[i][j] * Vv[k][j];
        M[i][k] = s;
    }
    __syncthreads();

    // A = M - N N^T  (N = V - I), write straight out
    for (int idx = t; idx < DIM * DIM; idx += 128) {
        int i = idx / DIM, k = idx % DIM;
        double s = 0;
        for (int j = 0; j < DIM; j++) {
            double ni = Vv[i][j] - (i == j ? 1.0 : 0.0);
            double nk = Vv[k][j] - (k == j ? 1.0 : 0.0);
            s += ni * nk;
        }
        ws[idx] = (float)(M[i][k] - s);
    }

    // Vb, VTc
    if (t < DIM) {
        double s = 0;
        for (int j = 0; j < DIM; j++) s += Vv[t][j] * (double)b[j];
        Vb[t] = s;
        double s2 = 0;
        for (int j = 0; j < DIM; j++) s2 += Vv[j][t] * cvec[j];
        VTc[t] = s2;
    }
    __syncthreads();

    // p
    if (t < DIM) {
        double s = 0;
        for (int j = 0; j < DIM; j++) {
            double nm = Vv[t][j] - (t == j ? 1.0 : 0.0);
            s += 2.0 * M[t][j] * cvec[j] - 2.0 * nm * VTc[j];
        }
        ws[100 + t] = (float)(s + Vb[t]);
    }
    __syncthreads();

    // q
    if (t == 0) {
        double cMc = 0, cVb = 0, n0 = 0;
        for (int i = 0; i < DIM; i++) {
            for (int j = 0; j < DIM; j++) cMc += cvec[i] * M[i][j] * cvec[j];
            cVb += cvec[i] * Vb[i];
            n0 += VTc[i] * VTc[i];
        }
        ws[110] = (float)(cMc + cVb - n0);
    }
}

// ---------------------------------------------------------------------------
// Kernel 2: one thread per (b,s) sample.
//   gather e1,e2 rows (5x float2 each), rel row; cc[k]=sum_j e1[j]*e2[(j+k)%10]
//   x = r * cc ; out = q + p.x + x A x
// ---------------------------------------------------------------------------
__global__ __launch_bounds__(256) void harmon_main(
    const int* __restrict__ samples, const float* __restrict__ ent,
    const float* __restrict__ rel, const float* __restrict__ ws,
    float* __restrict__ out, int n) {
    int tid = blockIdx.x * 256 + threadIdx.x;
    if (tid >= n) return;

    int i1 = samples[3 * tid + 0];
    int ir = samples[3 * tid + 1];
    int i2 = samples[3 * tid + 2];

    const float2* p1 = (const float2*)(ent + (size_t)i1 * DIM);
    const float2* p2 = (const float2*)(ent + (size_t)i2 * DIM);
    const float2* pr = (const float2*)(rel + (size_t)ir * DIM);

    float a[DIM], e[DIM], r[DIM];
#pragma unroll
    for (int i = 0; i < 5; i++) {
        float2 v1 = p1[i]; a[2 * i] = v1.x; a[2 * i + 1] = v1.y;
        float2 v2 = p2[i]; e[2 * i] = v2.x; e[2 * i + 1] = v2.y;
        float2 vr = pr[i]; r[2 * i] = vr.x; r[2 * i + 1] = vr.y;
    }

    float x[DIM];
#pragma unroll
    for (int k = 0; k < DIM; k++) {
        float s = 0.0f;
#pragma unroll
        for (int j = 0; j < DIM; j++) s = fmaf(a[j], e[(j + k) % DIM], s);
        x[k] = r[k] * s;
    }

    float acc = ws[110];
#pragma unroll
    for (int k = 0; k < DIM; k++) {
        float s = ws[100 + k];
#pragma unroll
        for (int t = 0; t < DIM; t++) s = fmaf(ws[k * DIM + t], x[t], s);
        acc = fmaf(x[k], s, acc);
    }
    out[tid] = acc;
}

extern "C" void kernel_launch(void* const* d_in, const int* in_sizes, int n_in,
                              void* d_out, int out_size, void* d_ws, size_t ws_size,
                              hipStream_t stream) {
    const int* samples = (const int*)d_in[0];
    const float* ent = (const float*)d_in[1];
    const float* rel = (const float*)d_in[2];
    const float* W = (const float*)d_in[3];
    const float* b = (const float*)d_in[4];
    float* out = (float*)d_out;
    float* ws = (float*)d_ws;

    int n = in_sizes[0] / 3; // B*S samples

    harmon_setup<<<1, 128, 0, stream>>>(W, b, ws);
    int blocks = (n + 255) / 256;
    harmon_main<<<blocks, 256, 0, stream>>>(samples, ent, rel, ws, out, n);
}